// Round 1
// baseline (487.462 us; speedup 1.0000x reference)
//
#include <hip/hip_runtime.h>
#include <hip/hip_bf16.h>
#include <math.h>

#define CB   128   // input channels
#define CMID 64    // compressed channels
#define NENC 100   // encoder out channels (25 * 2 * 2)
#define HH   48
#define WW   48
#define BB   4
#define HW   (HH*WW)          // 2304
#define H2   (HH*2)           // 96
#define W2   (WW*2)           // 96

// ---------------- Kernel 1: per-batch gamma ----------------
__global__ void gamma_kernel(const float* __restrict__ x, float* __restrict__ gamma) {
    int b = blockIdx.x;
    const float* xb = x + (size_t)b * CB * HW;
    float s = 0.f, s2 = 0.f;
    for (int i = threadIdx.x; i < HW; i += blockDim.x) {
        float g = 0.299f * xb[i] + 0.587f * xb[HW + i] + 0.114f * xb[2 * HW + i];
        s += g; s2 += g * g;
    }
    // wave (64-lane) reduce
    for (int o = 32; o > 0; o >>= 1) {
        s  += __shfl_down(s, o);
        s2 += __shfl_down(s2, o);
    }
    __shared__ float ss[4], ss2[4];
    int wid = threadIdx.x >> 6;
    if ((threadIdx.x & 63) == 0) { ss[wid] = s; ss2[wid] = s2; }
    __syncthreads();
    if (threadIdx.x == 0) {
        float S = 0.f, S2 = 0.f;
        int nw = blockDim.x >> 6;
        for (int i = 0; i < nw; i++) { S += ss[i]; S2 += ss2[i]; }
        const float N = (float)HW;
        float gm = S / N;
        float var = (S2 - S * S / N) / (N - 1.0f);
        var = fmaxf(var, 0.f);
        float gs = sqrtf(var);
        float gam = 0.8f + 0.4f * gm / (gm + fmaxf(gs, 1e-6f));
        gam = fminf(fmaxf(gam, 0.8f), 1.2f);
        gamma[b] = gam;
    }
}

// ---------------- Kernel 2: xg = pow(x + eps, gamma[b]) ----------------
__global__ void pow_kernel(const float* __restrict__ x, const float* __restrict__ gamma,
                           float* __restrict__ xg) {
    int idx = blockIdx.x * blockDim.x + threadIdx.x;
    const int total = BB * CB * HW;
    if (idx >= total) return;
    int b = idx / (CB * HW);
    xg[idx] = powf(x[idx] + 1e-6f, gamma[b]);
}

// ---------------- Kernel 3: conv1x1 + BN + SiLU ----------------
__global__ void conv1_kernel(const float* __restrict__ xg, const float* __restrict__ w,
                             const float* __restrict__ g, const float* __restrict__ bta,
                             const float* __restrict__ m, const float* __restrict__ v,
                             float* __restrict__ y1) {
    int idx = blockIdx.x * blockDim.x + threadIdx.x;
    const int total = BB * CMID * HW;
    if (idx >= total) return;
    int p  = idx % HW;
    int cm = (idx / HW) % CMID;
    int b  = idx / (CMID * HW);
    const float* xb = xg + (size_t)b * CB * HW + p;
    const float* wc = w + cm * CB;
    float acc = 0.f;
#pragma unroll 8
    for (int c = 0; c < CB; c++) acc += wc[c] * xb[(size_t)c * HW];
    float sc = g[cm] * rsqrtf(v[cm] + 1e-3f);
    float y = (acc - m[cm]) * sc + bta[cm];
    y1[idx] = y / (1.f + expf(-y));   // SiLU
}

// ---------------- Kernel 4: conv3x3 + BN ----------------
__global__ void conv3_kernel(const float* __restrict__ y1, const float* __restrict__ w,
                             const float* __restrict__ g, const float* __restrict__ bta,
                             const float* __restrict__ m, const float* __restrict__ v,
                             float* __restrict__ wk2) {
    int idx = blockIdx.x * blockDim.x + threadIdx.x;
    const int total = BB * NENC * HW;
    if (idx >= total) return;
    int wc = idx % WW;
    int h  = (idx / WW) % HH;
    int e  = (idx / HW) % NENC;
    int b  = idx / (NENC * HW);
    const float* wptr = w + (size_t)e * CMID * 9;
    const float* yb   = y1 + (size_t)b * CMID * HW;
    float acc = 0.f;
    for (int cm = 0; cm < CMID; cm++) {
        const float* yc = yb + (size_t)cm * HW;
        const float* wk = wptr + cm * 9;
#pragma unroll
        for (int dy = -1; dy <= 1; dy++) {
            int hy = h + dy;
            if (hy < 0 || hy >= HH) continue;
#pragma unroll
            for (int dx = -1; dx <= 1; dx++) {
                int wx = wc + dx;
                if (wx < 0 || wx >= WW) continue;
                acc += wk[(dy + 1) * 3 + (dx + 1)] * yc[hy * WW + wx];
            }
        }
    }
    float sc = g[e] * rsqrtf(v[e] + 1e-3f);
    wk2[idx] = (acc - m[e]) * sc + bta[e];
}

// ---------------- Kernel 5: softmax (pixel-shuffled) + CARAFE gather ----------------
// block = (b, H) output row; LDS holds 96 positions x 25 softmaxed weights
__global__ void carafe_kernel(const float* __restrict__ xg, const float* __restrict__ wk2,
                              float* __restrict__ out) {
    int b  = blockIdx.x / H2;
    int Hp = blockIdx.x % H2;
    int h  = Hp >> 1, si = Hp & 1;
    __shared__ float wsm[W2 * 25];

    for (int Wp = threadIdx.x; Wp < W2; Wp += blockDim.x) {
        int w = Wp >> 1, sj = Wp & 1;
        int off = 2 * si + sj;
        const float* base = wk2 + (size_t)b * NENC * HW + h * WW + w;
        float vals[25];
        float mx = -1e30f;
#pragma unroll
        for (int k = 0; k < 25; k++) {
            float t = base[(size_t)(4 * k + off) * HW];
            vals[k] = t; mx = fmaxf(mx, t);
        }
        float sum = 0.f;
#pragma unroll
        for (int k = 0; k < 25; k++) { float e = expf(vals[k] - mx); vals[k] = e; sum += e; }
        float inv = 1.f / sum;
#pragma unroll
        for (int k = 0; k < 25; k++) wsm[Wp * 25 + k] = vals[k] * inv;
    }
    __syncthreads();

    for (int lin = threadIdx.x; lin < CB * W2; lin += blockDim.x) {
        int Wp = lin % W2;
        int c  = lin / W2;
        int w  = Wp >> 1;
        const float* xb = xg + ((size_t)b * CB + c) * HW;
        const float* wp = wsm + Wp * 25;
        float acc = 0.f;
#pragma unroll
        for (int i = 0; i < 5; i++) {
            int hy = h + i - 2;
            if (hy < 0 || hy >= HH) continue;
#pragma unroll
            for (int j = 0; j < 5; j++) {
                int wx = w + j - 2;
                if (wx < 0 || wx >= WW) continue;
                acc += wp[i * 5 + j] * xb[hy * WW + wx];
            }
        }
        out[(((size_t)b * CB + c) * H2 + Hp) * W2 + Wp] = acc;
    }
}

extern "C" void kernel_launch(void* const* d_in, const int* in_sizes, int n_in,
                              void* d_out, int out_size, void* d_ws, size_t ws_size,
                              hipStream_t stream) {
    const float* x       = (const float*)d_in[0];
    const float* comp_w  = (const float*)d_in[1];
    const float* comp_g  = (const float*)d_in[2];
    const float* comp_b  = (const float*)d_in[3];
    const float* comp_m  = (const float*)d_in[4];
    const float* comp_v  = (const float*)d_in[5];
    const float* enc_w   = (const float*)d_in[6];
    const float* enc_g   = (const float*)d_in[7];
    const float* enc_b   = (const float*)d_in[8];
    const float* enc_m   = (const float*)d_in[9];
    const float* enc_v   = (const float*)d_in[10];
    float* out = (float*)d_out;

    float* ws = (float*)d_ws;
    float* gamma = ws;                                  // 4
    float* xg    = ws + 64;                             // 1,179,648
    float* y1    = xg + (size_t)BB * CB * HW;           // 589,824
    float* wk2   = y1 + (size_t)BB * CMID * HW;         // 921,600

    gamma_kernel<<<BB, 256, 0, stream>>>(x, gamma);

    {
        int total = BB * CB * HW;
        pow_kernel<<<(total + 255) / 256, 256, 0, stream>>>(x, gamma, xg);
    }
    {
        int total = BB * CMID * HW;
        conv1_kernel<<<(total + 255) / 256, 256, 0, stream>>>(
            xg, comp_w, comp_g, comp_b, comp_m, comp_v, y1);
    }
    {
        int total = BB * NENC * HW;
        conv3_kernel<<<(total + 255) / 256, 256, 0, stream>>>(
            y1, enc_w, enc_g, enc_b, enc_m, enc_v, wk2);
    }
    carafe_kernel<<<BB * H2, 256, 0, stream>>>(xg, wk2, out);
}

// Round 4
// 223.423 us; speedup vs baseline: 2.1818x; 2.1818x over previous
//
#include <hip/hip_runtime.h>
#include <hip/hip_bf16.h>
#include <math.h>

#define CB   128   // input channels
#define CMID 64    // compressed channels
#define NENC 100   // encoder out channels (25 * 2 * 2)
#define HH   48
#define WW   48
#define BB   4
#define HW   (HH*WW)          // 2304
#define H2   (HH*2)           // 96
#define W2   (WW*2)           // 96

// ---------------- Kernel 1: per-batch gamma ----------------
__global__ void gamma_kernel(const float* __restrict__ x, float* __restrict__ gamma) {
    int b = blockIdx.x;
    const float* xb = x + (size_t)b * CB * HW;
    float s = 0.f, s2 = 0.f;
    for (int i = threadIdx.x; i < HW; i += blockDim.x) {
        float g = 0.299f * xb[i] + 0.587f * xb[HW + i] + 0.114f * xb[2 * HW + i];
        s += g; s2 += g * g;
    }
    for (int o = 32; o > 0; o >>= 1) {
        s  += __shfl_down(s, o);
        s2 += __shfl_down(s2, o);
    }
    __shared__ float ss[4], ss2[4];
    int wid = threadIdx.x >> 6;
    if ((threadIdx.x & 63) == 0) { ss[wid] = s; ss2[wid] = s2; }
    __syncthreads();
    if (threadIdx.x == 0) {
        float S = 0.f, S2 = 0.f;
        int nw = blockDim.x >> 6;
        for (int i = 0; i < nw; i++) { S += ss[i]; S2 += ss2[i]; }
        const float N = (float)HW;
        float gm = S / N;
        float var = (S2 - S * S / N) / (N - 1.0f);
        var = fmaxf(var, 0.f);
        float gs = sqrtf(var);
        float gam = 0.8f + 0.4f * gm / (gm + fmaxf(gs, 1e-6f));
        gam = fminf(fmaxf(gam, 0.8f), 1.2f);
        gamma[b] = gam;
    }
}

// ---------------- Kernel 2: xg = pow(x + eps, gamma[b]), float4 ----------------
__global__ void pow_kernel(const float* __restrict__ x, const float* __restrict__ gamma,
                           float* __restrict__ xg) {
    int idx = blockIdx.x * blockDim.x + threadIdx.x;
    const int total4 = BB * CB * HW / 4;
    if (idx >= total4) return;
    int b = idx / (CB * HW / 4);
    float gam = gamma[b];
    float4 xv = ((const float4*)x)[idx];
    float4 r;
    r.x = powf(xv.x + 1e-6f, gam);
    r.y = powf(xv.y + 1e-6f, gam);
    r.z = powf(xv.z + 1e-6f, gam);
    r.w = powf(xv.w + 1e-6f, gam);
    ((float4*)xg)[idx] = r;
}

// ---------------- Kernel 3: conv1x1 + BN + SiLU, float4 over pixels ----------------
__global__ void conv1_kernel(const float* __restrict__ xg, const float* __restrict__ w,
                             const float* __restrict__ g, const float* __restrict__ bta,
                             const float* __restrict__ m, const float* __restrict__ vv,
                             float* __restrict__ y1) {
    int idx = blockIdx.x * blockDim.x + threadIdx.x;
    const int PG = HW / 4;                 // 576 pixel-groups
    const int total = BB * CMID * PG;
    if (idx >= total) return;
    int pg = idx % PG;
    int cm = (idx / PG) % CMID;
    int b  = idx / (CMID * PG);
    const float4* xb = (const float4*)(xg + (size_t)b * CB * HW) + pg;
    const float* wc = w + cm * CB;
    float4 acc = {0.f, 0.f, 0.f, 0.f};
#pragma unroll 4
    for (int c = 0; c < CB; c++) {
        float4 xv = xb[(size_t)c * PG];
        float wv = wc[c];
        acc.x = fmaf(wv, xv.x, acc.x);
        acc.y = fmaf(wv, xv.y, acc.y);
        acc.z = fmaf(wv, xv.z, acc.z);
        acc.w = fmaf(wv, xv.w, acc.w);
    }
    float sc = g[cm] * rsqrtf(vv[cm] + 1e-3f);
    float sh = bta[cm] - m[cm] * sc;
    float4 o;
    float t;
    t = acc.x * sc + sh; o.x = t / (1.f + expf(-t));
    t = acc.y * sc + sh; o.y = t / (1.f + expf(-t));
    t = acc.z * sc + sh; o.z = t / (1.f + expf(-t));
    t = acc.w * sc + sh; o.w = t / (1.f + expf(-t));
    ((float4*)y1)[idx] = o;
}

// ---------------- Kernel 4: conv3x3 + BN ----------------
// block = (b, e); 192 threads = 48 rows x 4 quarter-rows of 12 outputs.
// Weights are wave-uniform (scalar loads); row data loaded as aligned float4,
// all 9-tap FMAs run from registers.
__global__ __launch_bounds__(192) void conv3_kernel(
        const float* __restrict__ y1, const float* __restrict__ w,
        const float* __restrict__ g, const float* __restrict__ bta,
        const float* __restrict__ m, const float* __restrict__ vv,
        float* __restrict__ wk2) {
    int be = blockIdx.x;
    int b = be / NENC, e = be % NENC;
    int t = threadIdx.x;
    int q = t & 3, row = t >> 2;           // row 0..47, quarter 0..3
    int c0 = q * 12;
    const float* wbase = w + (size_t)e * CMID * 9;
    const float* yb = y1 + (size_t)b * CMID * HW;
    float acc[12];
#pragma unroll
    for (int j = 0; j < 12; j++) acc[j] = 0.f;

    for (int cm = 0; cm < CMID; cm++) {
        const float* yc = yb + (size_t)cm * HW;
        const float* wk = wbase + cm * 9;
        float wr[9];
#pragma unroll
        for (int i = 0; i < 9; i++) wr[i] = wk[i];
#pragma unroll
        for (int r = 0; r < 3; r++) {
            int hy = row + r - 1;
            if (hy < 0 || hy >= HH) continue;
            const float* yr = yc + hy * WW + c0;
            float4 a  = *(const float4*)(yr);
            float4 bq = *(const float4*)(yr + 4);
            float4 cq = *(const float4*)(yr + 8);
            float v0  = (c0 == 0) ? 0.f : yr[-1];
            float v13 = (c0 + 12 >= WW) ? 0.f : yr[12];
            float vbuf[14] = {v0, a.x, a.y, a.z, a.w,
                              bq.x, bq.y, bq.z, bq.w,
                              cq.x, cq.y, cq.z, cq.w, v13};
            float wa = wr[r * 3 + 0], wb2 = wr[r * 3 + 1], wc2 = wr[r * 3 + 2];
#pragma unroll
            for (int j = 0; j < 12; j++)
                acc[j] = fmaf(wa, vbuf[j], fmaf(wb2, vbuf[j + 1], fmaf(wc2, vbuf[j + 2], acc[j])));
        }
    }
    float sc = g[e] * rsqrtf(vv[e] + 1e-3f);
    float sh = bta[e] - m[e] * sc;
    float* outp = wk2 + (size_t)(b * NENC + e) * HW + row * WW + c0;
#pragma unroll
    for (int j = 0; j < 12; j++) outp[j] = acc[j] * sc + sh;
}

// ---------------- Kernel 5: pixel-shuffled softmax -> wsm[b][25][H2][W2] ----------------
__global__ void softmax_kernel(const float* __restrict__ wk2, float* __restrict__ wsm) {
    int idx = blockIdx.x * blockDim.x + threadIdx.x;
    const int total = BB * H2 * W2;
    if (idx >= total) return;
    int Wp = idx % W2, Hp = (idx / W2) % H2, b = idx / (H2 * W2);
    int h = Hp >> 1, w = Wp >> 1;
    int off = 2 * (Hp & 1) + (Wp & 1);
    const float* base = wk2 + (size_t)b * NENC * HW + (size_t)off * HW + h * WW + w;
    float vals[25];
    float mx = -1e30f;
#pragma unroll
    for (int k = 0; k < 25; k++) {
        float tv = base[(size_t)(4 * k) * HW];
        vals[k] = tv; mx = fmaxf(mx, tv);
    }
    float sum = 0.f;
#pragma unroll
    for (int k = 0; k < 25; k++) { float e2 = expf(vals[k] - mx); vals[k] = e2; sum += e2; }
    float inv = 1.f / sum;
#pragma unroll
    for (int k = 0; k < 25; k++)
        wsm[((size_t)(b * 25 + k) * H2 + Hp) * W2 + Wp] = vals[k] * inv;
}

// ---------------- Kernel 6: CARAFE gather ----------------
// thread = (b,c,h,w): 25 shared x-loads feed all 4 sub-pixel outputs (100 FMA).
__global__ void gather_kernel(const float* __restrict__ xg, const float* __restrict__ wsm,
                              float* __restrict__ out) {
    int idx = blockIdx.x * blockDim.x + threadIdx.x;
    const int total = BB * CB * HW;
    if (idx >= total) return;
    int w = idx % WW;
    int h = (idx / WW) % HH;
    int c = (idx / HW) % CB;
    int b = idx / (CB * HW);
    const float* xb = xg + ((size_t)b * CB + c) * HW;
    float xv[25];
#pragma unroll
    for (int i = 0; i < 5; i++) {
        int hy = h + i - 2;
        bool hok = (hy >= 0) && (hy < HH);
#pragma unroll
        for (int j = 0; j < 5; j++) {
            int wx = w + j - 2;
            bool ok = hok && (wx >= 0) && (wx < WW);
            xv[i * 5 + j] = ok ? xb[hy * WW + wx] : 0.f;
        }
    }
    float a0 = 0.f, a1 = 0.f, a2 = 0.f, a3 = 0.f;
    const float* wb = wsm + (size_t)b * 25 * H2 * W2;
    int r0 = (2 * h) * W2 + 2 * w;
#pragma unroll
    for (int k = 0; k < 25; k++) {
        const float* wkp = wb + (size_t)k * H2 * W2;
        float2 w0 = *(const float2*)(wkp + r0);
        float2 w1 = *(const float2*)(wkp + r0 + W2);
        float xk = xv[k];
        a0 = fmaf(w0.x, xk, a0);
        a1 = fmaf(w0.y, xk, a1);
        a2 = fmaf(w1.x, xk, a2);
        a3 = fmaf(w1.y, xk, a3);
    }
    float* ob = out + (((size_t)b * CB + c) * H2 + 2 * h) * W2 + 2 * w;
    float2 s0 = {a0, a1};
    float2 s1 = {a2, a3};
    *(float2*)ob = s0;
    *(float2*)(ob + W2) = s1;
}

extern "C" void kernel_launch(void* const* d_in, const int* in_sizes, int n_in,
                              void* d_out, int out_size, void* d_ws, size_t ws_size,
                              hipStream_t stream) {
    const float* x       = (const float*)d_in[0];
    const float* comp_w  = (const float*)d_in[1];
    const float* comp_g  = (const float*)d_in[2];
    const float* comp_b  = (const float*)d_in[3];
    const float* comp_m  = (const float*)d_in[4];
    const float* comp_v  = (const float*)d_in[5];
    const float* enc_w   = (const float*)d_in[6];
    const float* enc_g   = (const float*)d_in[7];
    const float* enc_b   = (const float*)d_in[8];
    const float* enc_m   = (const float*)d_in[9];
    const float* enc_v   = (const float*)d_in[10];
    float* out = (float*)d_out;

    float* ws = (float*)d_ws;
    float* gamma = ws;                                   // 64 (padded)
    float* xg    = ws + 64;                              // 1,179,648
    float* wk2   = xg + (size_t)BB * CB * HW;            // 921,600
    float* y1    = wk2 + (size_t)BB * NENC * HW;         // 589,824 (dead after conv3)
    float* wsm   = y1;                                   // 921,600 (overlays y1; needs its own tail)
    // total floats: 64 + 1179648 + 921600 + 921600 = 3,022,912 (~12.1 MB)

    gamma_kernel<<<BB, 256, 0, stream>>>(x, gamma);

    {
        int total4 = BB * CB * HW / 4;
        pow_kernel<<<(total4 + 255) / 256, 256, 0, stream>>>(x, gamma, xg);
    }
    {
        int total = BB * CMID * (HW / 4);
        conv1_kernel<<<(total + 255) / 256, 256, 0, stream>>>(
            xg, comp_w, comp_g, comp_b, comp_m, comp_v, y1);
    }
    conv3_kernel<<<BB * NENC, 192, 0, stream>>>(
        y1, enc_w, enc_g, enc_b, enc_m, enc_v, wk2);
    {
        int total = BB * H2 * W2;
        softmax_kernel<<<(total + 255) / 256, 256, 0, stream>>>(wk2, wsm);
    }
    {
        int total = BB * CB * HW;
        gather_kernel<<<(total + 255) / 256, 256, 0, stream>>>(xg, wsm, out);
    }
}